// Round 2
// baseline (283.842 us; speedup 1.0000x reference)
//
#include <hip/hip_runtime.h>
#include <math.h>

#define TBL 2048
#define E_PB 8

// workspace layout (float offsets)
#define OFF_V      0        // 64
#define OFF_S0     64       // 1
#define OFF_MM     66       // 2 uints (encoded min/max)
#define OFF_C2     128      // 128
#define OFF_EMB    256      // 128
#define OFF_M      512      // 128*64
#define OFF_WGT    8704     // 32*128 accumulator copies
#define OFF_W2T    12800    // 512*256
#define OFF_W3T    143872   // 256*128
#define OFF_SCORES 176640   // N

__device__ __forceinline__ unsigned encf(float f) {
    unsigned u = __float_as_uint(f);
    return (u & 0x80000000u) ? ~u : (u | 0x80000000u);
}
__device__ __forceinline__ float decf(unsigned u) {
    return __uint_as_float((u & 0x80000000u) ? (u & 0x7fffffffu) : ~u);
}

// ---------------- K1: fold weights, transpose W2/W3, init accumulators ----
__global__ void __launch_bounds__(256) k1_prep(
        const float* __restrict__ X,  const float* __restrict__ We,
        const float* __restrict__ be, const float* __restrict__ Wv,
        const float* __restrict__ Wq, const float* __restrict__ bq,
        const float* __restrict__ Wk, const float* __restrict__ bk,
        const float* __restrict__ W2, const float* __restrict__ W3,
        const int* __restrict__ selfp, float* ws)
{
    const int b = blockIdx.x, t = threadIdx.x;
    if (b == 0) {
        __shared__ float emb[128], q[128], u[128];
        const int self = *selfp;
        const float* xs = X + (size_t)self * 64;
        if (t < 128) {
            float acc = be[t];
            for (int d = 0; d < 64; ++d) acc = __builtin_fmaf(We[t*64 + d], xs[d], acc);
            emb[t] = acc;
            ws[OFF_EMB + t] = acc;
        }
        __syncthreads();
        if (t < 128) {
            float acc = bq[t];
            for (int f = 0; f < 128; ++f) acc = __builtin_fmaf(Wq[t*128 + f], emb[f], acc);
            q[t] = acc;
        }
        __syncthreads();
        if (t < 128) {
            float acc = 0.f;
            for (int e = 0; e < 128; ++e) acc = __builtin_fmaf(Wk[e*128 + t], q[e], acc);
            u[t] = acc;
        }
        __syncthreads();
        const float rs = 0.08838834764831845f;  // 1/sqrt(128)
        if (t < 64) {
            float acc = 0.f;
            for (int e = 0; e < 128; ++e) acc = __builtin_fmaf(We[e*64 + t], u[e], acc);
            ws[OFF_V + t] = acc * rs;
        }
        if (t == 0) {
            float acc = 0.f;
            for (int e = 0; e < 128; ++e) acc += be[e]*u[e] + bk[e]*q[e];
            ws[OFF_S0] = acc * rs;
            unsigned* mm = (unsigned*)(ws + OFF_MM);
            mm[0] = 0xFFFFFFFFu;  // encoded min init (largest)
            mm[1] = 0u;           // encoded max init (smallest)
        }
        for (int i = t; i < 32*128; i += 256) ws[OFF_WGT + i] = 0.f;
    } else if (b <= 128) {
        const int r = b - 1;  // M row r = (Wv @ We)[r], c2[r] = (Wv @ be)[r]
        if (t < 64) {
            float acc = 0.f;
            for (int e = 0; e < 128; ++e) acc = __builtin_fmaf(Wv[r*128 + e], We[e*64 + t], acc);
            ws[OFF_M + r*64 + t] = acc;
        } else if (t == 64) {
            float acc = 0.f;
            for (int e = 0; e < 128; ++e) acc = __builtin_fmaf(Wv[r*128 + e], be[e], acc);
            ws[OFF_C2 + r] = acc;
        }
    } else if (b <= 192) {
        const int base = (b - 129) * 2048;   // W2T[512][256] = W2[256][512]^T
        for (int i = t; i < 2048; i += 256) {
            const int idx = base + i;
            const int k = idx >> 8, c = idx & 255;
            ws[OFF_W2T + idx] = W2[c*512 + k];
        }
    } else {
        const int base = (b - 193) * 2048;   // W3T[256][128] = W3[128][256]^T
        for (int i = t; i < 2048; i += 256) {
            const int idx = base + i;
            const int k = idx >> 7, c = idx & 127;
            ws[OFF_W3T + idx] = W3[c*256 + k];
        }
    }
}

// ---------------- K2: scores = X@v + s0, plus global min/max --------------
__global__ void __launch_bounds__(256) k2_scores(const float4* __restrict__ X4,
                                                 float* ws, int N)
{
    const int t = threadIdx.x;
    const int lane = t & 63;
    const int wv = t >> 6;        // wave in block
    const int grp = lane >> 4;    // agent slot in wave
    const int l16 = lane & 15;    // lane within 16-lane agent group
    const float4 vch = *(const float4*)(ws + OFF_V + l16*4);
    const float s0 = ws[OFF_S0];
    float* scores = ws + OFF_SCORES;
    float smin = INFINITY, smax = -INFINITY;
    const int iters = (N + 15) >> 4;
    for (int it = blockIdx.x; it < iters; it += gridDim.x) {
        const int n = it*16 + wv*4 + grp;
        const bool ok = (n < N);
        float s = 0.f;
        if (ok) {
            const float4 xv = X4[(size_t)n*16 + l16];
            s = xv.x*vch.x + xv.y*vch.y + xv.z*vch.z + xv.w*vch.w;
        }
        s += __shfl_xor(s, 1);
        s += __shfl_xor(s, 2);
        s += __shfl_xor(s, 4);
        s += __shfl_xor(s, 8);
        s += s0;
        if (ok) {
            if (l16 == 0) scores[n] = s;
            smin = fminf(smin, s);
            smax = fmaxf(smax, s);
        }
    }
    #pragma unroll
    for (int m = 32; m >= 1; m >>= 1) {
        smin = fminf(smin, __shfl_xor(smin, m));
        smax = fmaxf(smax, __shfl_xor(smax, m));
    }
    __shared__ float rmn[4], rmx[4];
    if (lane == 0) { rmn[wv] = smin; rmx[wv] = smax; }
    __syncthreads();
    if (t == 0) {
        const float mn = fminf(fminf(rmn[0], rmn[1]), fminf(rmn[2], rmn[3]));
        const float mx = fmaxf(fmaxf(rmx[0], rmx[1]), fmaxf(rmx[2], rmx[3]));
        atomicMin((unsigned*)(ws + OFF_MM), encf(mn));
        atomicMax((unsigned*)(ws + OFF_MM) + 1, encf(mx));
    }
}

// ---------------- K3: build softmax-weight table over [smin, smax] --------
// LDS-staged weight chunks so the inner loops never touch L2.
__global__ void __launch_bounds__(256) k3_table(
        const float* __restrict__ W1, const float* __restrict__ b1,
        const float* __restrict__ b2, const float* __restrict__ b3,
        float* ws, int offTab)
{
    __shared__ float h1[E_PB][512];      // 16KB
    __shared__ float stage[8192];        // 32KB ([32][256] for L2, [64][128] for L3)
    __shared__ float h2[E_PB][256];      // 8KB
    __shared__ float sm[E_PB][128];      // 4KB   total 60KB
    const int t = threadIdx.x;
    const unsigned* mm = (const unsigned*)(ws + OFF_MM);
    const float smin = decf(mm[0]);
    const float smax = decf(mm[1]);
    const float step = (smax - smin) / (float)(TBL - 1);
    const int e0 = blockIdx.x * E_PB;

    for (int idx = t; idx < E_PB*512; idx += 256) {   // layer 1 (scalar -> 512)
        const int e = idx >> 9, k = idx & 511;
        const float s = smin + step * (float)(e0 + e);
        h1[e][k] = fmaxf(0.f, __builtin_fmaf(s, W1[k], b1[k]));
    }

    {   // layer 2: thread t owns output column t, 8 entries; k staged in LDS
        float acc[E_PB];
        const float bb = b2[t];
        #pragma unroll
        for (int e = 0; e < E_PB; ++e) acc[e] = bb;
        const float* w2t = ws + OFF_W2T;
        for (int c0 = 0; c0 < 512; c0 += 32) {
            __syncthreads();   // first iter also guards h1 writes
            for (int i = t; i < 32*256/4; i += 256)
                ((float4*)stage)[i] = ((const float4*)(w2t + c0*256))[i];
            __syncthreads();
            #pragma unroll
            for (int kk = 0; kk < 32; ++kk) {
                const float w = stage[kk*256 + t];
                #pragma unroll
                for (int e = 0; e < E_PB; ++e)
                    acc[e] = __builtin_fmaf(w, h1[e][c0 + kk], acc[e]);
            }
        }
        #pragma unroll
        for (int e = 0; e < E_PB; ++e) h2[e][t] = fmaxf(0.f, acc[e]);
    }

    {   // layer 3: c = t&127, half = t>>7 covers 4 entries; k staged in LDS
        const int c = t & 127, hf = t >> 7;
        float acc[4];
        const float bb = b3[c];
        #pragma unroll
        for (int e = 0; e < 4; ++e) acc[e] = bb;
        const float* w3t = ws + OFF_W3T;
        for (int c0 = 0; c0 < 256; c0 += 64) {
            __syncthreads();   // first iter also guards h2 writes
            for (int i = t; i < 64*128/4; i += 256)
                ((float4*)stage)[i] = ((const float4*)(w3t + c0*128))[i];
            __syncthreads();
            #pragma unroll
            for (int kk = 0; kk < 64; ++kk) {
                const float w = stage[kk*128 + c];
                #pragma unroll
                for (int e = 0; e < 4; ++e)
                    acc[e] = __builtin_fmaf(w, h2[hf*4 + e][c0 + kk], acc[e]);
            }
        }
        #pragma unroll
        for (int e = 0; e < 4; ++e) sm[hf*4 + e][c] = fmaxf(0.f, acc[e]);
    }
    __syncthreads();
    if (t < 128) {   // softmax per entry (16 lanes per entry), write pair table
        const int e = t >> 4, l = t & 15;
        float m = -INFINITY;
        #pragma unroll
        for (int i = 0; i < 8; ++i) m = fmaxf(m, sm[e][l + 16*i]);
        #pragma unroll
        for (int msk = 1; msk < 16; msk <<= 1) m = fmaxf(m, __shfl_xor(m, msk));
        float p = 0.f;
        #pragma unroll
        for (int i = 0; i < 8; ++i) p += __expf(sm[e][l + 16*i] - m);
        #pragma unroll
        for (int msk = 1; msk < 16; msk <<= 1) p += __shfl_xor(p, msk);
        const float inv = 1.f / p;
        float* tab = ws + offTab;   // float2 pairs: tab[2*(row*128+c)] = {T[row], T[row+1]}
        const int row = e0 + e;
        #pragma unroll
        for (int i = 0; i < 8; ++i) {
            const int c = l + 16*i;
            const float wgt = __expf(sm[e][c] - m) * inv;
            if (row < TBL - 1) tab[2*(row*128 + c) + 0] = wgt;
            if (row >= 1)      tab[2*((row-1)*128 + c) + 1] = wgt;
        }
    }
}

// ---------------- K4: weighted_j = sum_n w_j(s_n) * (M[j]·x_n + c2_j) -----
// 512 threads = 4 agent-slots x 128 channels. M row in VGPRs (16xfloat4),
// x via ds_read_b128 broadcasts, one block per 64-agent chunk.
__global__ void __launch_bounds__(512) k4_main(const float4* __restrict__ X4,
        const int* __restrict__ selfp, float* ws, int N, int offTab)
{
    __shared__ float xs[64*64];       // 16KB
    const int t = threadIdx.x;
    const int j = t & 127;            // output channel
    const int slot = t >> 7;          // 0..3
    const int self = *selfp;
    const int base = blockIdx.x << 6;
    const int valid = min(64, N - base);

    for (int i = t; i < valid*16; i += 512)
        ((float4*)xs)[i] = X4[(size_t)base*16 + i];

    float4 Mr[16];
    #pragma unroll
    for (int d = 0; d < 16; ++d) Mr[d] = *(const float4*)(ws + OFF_M + j*64 + d*4);
    const float c2j = ws[OFF_C2 + j];
    const unsigned* mm = (const unsigned*)(ws + OFF_MM);
    const float smin = decf(mm[0]);
    const float smax = decf(mm[1]);
    const float inv_step = (smax > smin) ? (float)(TBL - 1) / (smax - smin) : 0.f;
    const float* scores = ws + OFF_SCORES;
    const float2* tabP = (const float2*)(ws + offTab);
    __syncthreads();

    float rho = 0.f;
    for (int a = slot; a < valid; a += 4) {
        const int n = base + a;
        const float s = scores[n];                 // wave-uniform -> scalar load
        const float fi = (s - smin) * inv_step;
        int ii = (int)fi;
        ii = max(0, min(TBL - 2, ii));
        const float f = fi - (float)ii;
        const float2 tp = tabP[ii*128 + j];        // coalesced 8B/lane from L2
        const float w = tp.x + f * (tp.y - tp.x);
        const float4* xa4 = (const float4*)(xs + a*64);  // LDS broadcast reads
        float ax = 0.f, ay = 0.f, az = 0.f, aw = 0.f;
        #pragma unroll
        for (int d = 0; d < 16; ++d) {
            const float4 xv = xa4[d];
            ax = __builtin_fmaf(Mr[d].x, xv.x, ax);
            ay = __builtin_fmaf(Mr[d].y, xv.y, ay);
            az = __builtin_fmaf(Mr[d].z, xv.z, az);
            aw = __builtin_fmaf(Mr[d].w, xv.w, aw);
        }
        const float val = (ax + ay) + (az + aw) + c2j;
        rho += (n == self) ? 0.f : w * val;
    }
    atomicAdd(&ws[OFF_WGT + ((blockIdx.x*4 + slot) & 31)*128 + j], rho);
}

// ---------------- K5: critic head ----------------------------------------
__global__ void __launch_bounds__(128) k5_final(
        const float* __restrict__ Wo1, const float* __restrict__ bo1,
        const float* __restrict__ Wo2, const float* __restrict__ bo2,
        float* ws, float* out)
{
    __shared__ float es[128], wg[128], red[128];
    const int t = threadIdx.x;
    es[t] = ws[OFF_EMB + t];
    float s = 0.f;
    for (int c = 0; c < 32; ++c) s += ws[OFF_WGT + c*128 + t];
    wg[t] = s;
    __syncthreads();
    float acc = bo1[t];
    for (int i = 0; i < 128; ++i) acc = __builtin_fmaf(Wo1[t*256 + i], es[i], acc);
    for (int i = 0; i < 128; ++i) acc = __builtin_fmaf(Wo1[t*256 + 128 + i], wg[i], acc);
    red[t] = fmaxf(acc, 0.f) * Wo2[t];
    __syncthreads();
    for (int m = 64; m >= 1; m >>= 1) {
        if (t < m) red[t] += red[t + m];
        __syncthreads();
    }
    if (t == 0) out[0] = red[0] + bo2[0];
}

extern "C" void kernel_launch(void* const* d_in, const int* in_sizes, int n_in,
                              void* d_out, int out_size, void* d_ws, size_t ws_size,
                              hipStream_t stream)
{
    const float* X   = (const float*)d_in[0];
    const float* We  = (const float*)d_in[1];
    const float* be  = (const float*)d_in[2];
    const float* Wv  = (const float*)d_in[3];
    const float* Wq  = (const float*)d_in[4];
    const float* bq  = (const float*)d_in[5];
    const float* Wk  = (const float*)d_in[6];
    const float* bk  = (const float*)d_in[7];
    const float* W1  = (const float*)d_in[8];
    const float* b1  = (const float*)d_in[9];
    const float* W2  = (const float*)d_in[10];
    const float* b2  = (const float*)d_in[11];
    const float* W3  = (const float*)d_in[12];
    const float* b3  = (const float*)d_in[13];
    const float* Wo1 = (const float*)d_in[14];
    const float* bo1 = (const float*)d_in[15];
    const float* Wo2 = (const float*)d_in[16];
    const float* bo2 = (const float*)d_in[17];
    const int* selfp = (const int*)d_in[18];
    float* ws = (float*)d_ws;
    float* out = (float*)d_out;

    const int N = in_sizes[0] / 64;
    const int offTab = OFF_SCORES + ((N + 63) & ~63);   // even -> float2-aligned
    const int nchunks = (N + 63) / 64;

    k1_prep<<<209, 256, 0, stream>>>(X, We, be, Wv, Wq, bq, Wk, bk, W2, W3, selfp, ws);
    k2_scores<<<1024, 256, 0, stream>>>((const float4*)X, ws, N);
    k3_table<<<TBL / E_PB, 256, 0, stream>>>(W1, b1, b2, b3, ws, offTab);
    k4_main<<<nchunks, 512, 0, stream>>>((const float4*)X, selfp, ws, N, offTab);
    k5_final<<<1, 128, 0, stream>>>(Wo1, bo1, Wo2, bo2, ws, out);
}

// Round 3
// 224.233 us; speedup vs baseline: 1.2658x; 1.2658x over previous
//
#include <hip/hip_runtime.h>
#include <math.h>

#define TBL 1024

// workspace layout (float offsets)
#define OFF_V      0        // 64
#define OFF_S0     64       // 1
#define OFF_MM     66       // 2 uints (encoded min/max)
#define OFF_C2     128      // 128
#define OFF_EMB    256      // 128
#define OFF_MT     512      // 64*128  (M transposed: Mt[d][j])
#define OFF_WGT    8704     // 32*128 accumulator copies
#define OFF_W1B1   12800    // 512*2 interleaved (W1[k], b1[k])
#define OFF_W2T    13824    // 512*256
#define OFF_W3T    144896   // 256*128
#define OFF_H2G    177664   // 256*1024  h2 transposed: h2g[c*1024 + e]
#define OFF_SCORES 439808   // N (padded); table follows at runtime offset

__device__ __forceinline__ unsigned encf(float f) {
    unsigned u = __float_as_uint(f);
    return (u & 0x80000000u) ? ~u : (u | 0x80000000u);
}
__device__ __forceinline__ float decf(unsigned u) {
    return __uint_as_float((u & 0x80000000u) ? (u & 0x7fffffffu) : ~u);
}

// ---------------- K1: fold weights, transposes, init accumulators --------
__global__ void __launch_bounds__(256) k1_prep(
        const float* __restrict__ X,  const float* __restrict__ We,
        const float* __restrict__ be, const float* __restrict__ Wv,
        const float* __restrict__ Wq, const float* __restrict__ bq,
        const float* __restrict__ Wk, const float* __restrict__ bk,
        const float* __restrict__ W1, const float* __restrict__ b1,
        const float* __restrict__ W2, const float* __restrict__ W3,
        const int* __restrict__ selfp, float* ws)
{
    const int b = blockIdx.x, t = threadIdx.x;
    if (b == 0) {
        __shared__ float emb[128], q[128], u[128];
        const int self = *selfp;
        const float* xs = X + (size_t)self * 64;
        if (t < 128) {
            float acc = be[t];
            for (int d = 0; d < 64; ++d) acc = __builtin_fmaf(We[t*64 + d], xs[d], acc);
            emb[t] = acc;
            ws[OFF_EMB + t] = acc;
        }
        __syncthreads();
        if (t < 128) {
            float acc = bq[t];
            for (int f = 0; f < 128; ++f) acc = __builtin_fmaf(Wq[t*128 + f], emb[f], acc);
            q[t] = acc;
        }
        __syncthreads();
        if (t < 128) {
            float acc = 0.f;
            for (int e = 0; e < 128; ++e) acc = __builtin_fmaf(Wk[e*128 + t], q[e], acc);
            u[t] = acc;
        }
        __syncthreads();
        const float rs = 0.08838834764831845f;  // 1/sqrt(128)
        if (t < 64) {
            float acc = 0.f;
            for (int e = 0; e < 128; ++e) acc = __builtin_fmaf(We[e*64 + t], u[e], acc);
            ws[OFF_V + t] = acc * rs;
        }
        if (t == 0) {
            float acc = 0.f;
            for (int e = 0; e < 128; ++e) acc += be[e]*u[e] + bk[e]*q[e];
            ws[OFF_S0] = acc * rs;
            unsigned* mm = (unsigned*)(ws + OFF_MM);
            mm[0] = 0xFFFFFFFFu;  // encoded min init (largest)
            mm[1] = 0u;           // encoded max init (smallest)
        }
        for (int i = t; i < 32*128; i += 256) ws[OFF_WGT + i] = 0.f;
    } else if (b <= 128) {
        const int r = b - 1;  // row r of M = (Wv @ We); store transposed Mt[d][r]
        if (t < 64) {
            float acc = 0.f;
            for (int e = 0; e < 128; ++e) acc = __builtin_fmaf(Wv[r*128 + e], We[e*64 + t], acc);
            ws[OFF_MT + t*128 + r] = acc;
        } else if (t == 64) {
            float acc = 0.f;
            for (int e = 0; e < 128; ++e) acc = __builtin_fmaf(Wv[r*128 + e], be[e], acc);
            ws[OFF_C2 + r] = acc;
        }
    } else if (b <= 192) {
        const int base = (b - 129) * 2048;   // W2T[512][256] = W2[256][512]^T
        for (int i = t; i < 2048; i += 256) {
            const int idx = base + i;
            const int k = idx >> 8, c = idx & 255;
            ws[OFF_W2T + idx] = W2[c*512 + k];
        }
    } else if (b <= 208) {
        const int base = (b - 193) * 2048;   // W3T[256][128] = W3[128][256]^T
        for (int i = t; i < 2048; i += 256) {
            const int idx = base + i;
            const int k = idx >> 7, c = idx & 127;
            ws[OFF_W3T + idx] = W3[c*256 + k];
        }
    } else {
        for (int k = t; k < 512; k += 256) {  // interleave (W1,b1) pairs
            ws[OFF_W1B1 + 2*k]     = W1[k];
            ws[OFF_W1B1 + 2*k + 1] = b1[k];
        }
    }
}

// ---------------- K2: scores = X@v + s0, plus global min/max --------------
__global__ void __launch_bounds__(256) k2_scores(const float4* __restrict__ X4,
                                                 float* ws, int N)
{
    const int t = threadIdx.x;
    const int lane = t & 63;
    const int wv = t >> 6;        // wave in block
    const int grp = lane >> 4;    // agent slot in wave
    const int l16 = lane & 15;    // lane within 16-lane agent group
    const float4 vch = *(const float4*)(ws + OFF_V + l16*4);
    const float s0 = ws[OFF_S0];
    float* scores = ws + OFF_SCORES;
    float smin = INFINITY, smax = -INFINITY;
    const int iters = (N + 15) >> 4;
    for (int it = blockIdx.x; it < iters; it += gridDim.x) {
        const int n = it*16 + wv*4 + grp;
        const bool ok = (n < N);
        float s = 0.f;
        if (ok) {
            const float4 xv = X4[(size_t)n*16 + l16];
            s = xv.x*vch.x + xv.y*vch.y + xv.z*vch.z + xv.w*vch.w;
        }
        s += __shfl_xor(s, 1);
        s += __shfl_xor(s, 2);
        s += __shfl_xor(s, 4);
        s += __shfl_xor(s, 8);
        s += s0;
        if (ok) {
            if (l16 == 0) scores[n] = s;
            smin = fminf(smin, s);
            smax = fmaxf(smax, s);
        }
    }
    #pragma unroll
    for (int m = 32; m >= 1; m >>= 1) {
        smin = fminf(smin, __shfl_xor(smin, m));
        smax = fmaxf(smax, __shfl_xor(smax, m));
    }
    __shared__ float rmn[4], rmx[4];
    if (lane == 0) { rmn[wv] = smin; rmx[wv] = smax; }
    __syncthreads();
    if (t == 0) {
        const float mn = fminf(fminf(rmn[0], rmn[1]), fminf(rmn[2], rmn[3]));
        const float mx = fmaxf(fmaxf(rmx[0], rmx[1]), fmaxf(rmx[2], rmx[3]));
        atomicMin((unsigned*)(ws + OFF_MM), encf(mn));
        atomicMax((unsigned*)(ws + OFF_MM) + 1, encf(mx));
    }
}

// ---------------- K3a: layers 1+2 fused -> h2g[c][e] ----------------------
// 256 blocks x 512 thr. Block b: entries e0=b*4. Thread: c=t&255, eh=t>>8.
// h1 recomputed from scalar-loaded (W1,b1) pairs; W2T read coalesced.
__global__ void __launch_bounds__(512) k3_l12(
        const float2* __restrict__ w1b1,   // [512] pairs (uniform -> s_load)
        const float* __restrict__ w2t,     // [512][256]
        const float* __restrict__ b2,
        const unsigned* __restrict__ mm,
        float* __restrict__ h2g)           // [256][1024]
{
    const int t = threadIdx.x;
    const int c = t & 255;
    const int eh = t >> 8;
    const float smin = decf(mm[0]);
    const float smax = decf(mm[1]);
    const float step = (smax - smin) / (float)(TBL - 1);
    const int eA = blockIdx.x*4 + eh*2;
    const float sA = smin + step * (float)eA;
    const float sB = smin + step * (float)(eA + 1);
    const float bb = b2[c];
    float a0 = bb, a1 = bb;
    #pragma unroll 8
    for (int k = 0; k < 512; ++k) {
        const float2 wb = w1b1[k];                 // uniform -> s_load
        const float w2v = w2t[k*256 + c];          // coalesced vmem
        const float h1A = fmaxf(0.f, __builtin_fmaf(sA, wb.x, wb.y));
        const float h1B = fmaxf(0.f, __builtin_fmaf(sB, wb.x, wb.y));
        a0 = __builtin_fmaf(w2v, h1A, a0);
        a1 = __builtin_fmaf(w2v, h1B, a1);
    }
    *(float2*)(h2g + c*1024 + eA) = make_float2(fmaxf(0.f, a0), fmaxf(0.f, a1));
}

// ---------------- K3b: layer 3 + softmax + pair table ---------------------
// 256 blocks x 256 thr. Block b: entries e0=b*4. Thread: j=t&127, kh=t>>7.
__global__ void __launch_bounds__(256) k3_l3(
        const float* __restrict__ h2g,     // [256][1024]
        const float* __restrict__ w3t,     // [256][128]
        const float* __restrict__ b3,
        const unsigned* __restrict__ mm,
        float* __restrict__ tab)           // pair table
{
    __shared__ float sm[4][128];
    const int t = threadIdx.x;
    const int j = t & 127;
    const int kh = t >> 7;
    const int e0 = blockIdx.x * 4;
    float acc[4] = {0.f, 0.f, 0.f, 0.f};
    #pragma unroll 8
    for (int kk = 0; kk < 128; ++kk) {
        const int k = kh*128 + kk;
        const float4 h2v = *(const float4*)(h2g + k*1024 + e0);  // uniform -> s_load
        const float w3v = w3t[k*128 + j];                        // coalesced vmem
        acc[0] = __builtin_fmaf(w3v, h2v.x, acc[0]);
        acc[1] = __builtin_fmaf(w3v, h2v.y, acc[1]);
        acc[2] = __builtin_fmaf(w3v, h2v.z, acc[2]);
        acc[3] = __builtin_fmaf(w3v, h2v.w, acc[3]);
    }
    if (kh == 0) {
        const float bb = b3[j];
        #pragma unroll
        for (int e = 0; e < 4; ++e) sm[e][j] = acc[e] + bb;
    }
    __syncthreads();
    if (kh == 1) {
        #pragma unroll
        for (int e = 0; e < 4; ++e) sm[e][j] = fmaxf(0.f, sm[e][j] + acc[e]);
    }
    __syncthreads();
    // softmax: wave w handles entry w (4 waves)
    const int w = t >> 6, lane = t & 63;
    const float v0 = sm[w][lane];
    const float v1 = sm[w][lane + 64];
    float m = fmaxf(v0, v1);
    #pragma unroll
    for (int msk = 1; msk < 64; msk <<= 1) m = fmaxf(m, __shfl_xor(m, msk));
    float p = __expf(v0 - m) + __expf(v1 - m);
    #pragma unroll
    for (int msk = 1; msk < 64; msk <<= 1) p += __shfl_xor(p, msk);
    const float inv = 1.f / p;
    const int row = e0 + w;
    const float g0 = __expf(v0 - m) * inv;
    const float g1 = __expf(v1 - m) * inv;
    if (row < TBL - 1) {
        tab[2*(row*128 + lane) + 0]      = g0;
        tab[2*(row*128 + lane + 64) + 0] = g1;
    }
    if (row >= 1) {
        tab[2*((row-1)*128 + lane) + 1]      = g0;
        tab[2*((row-1)*128 + lane + 64) + 1] = g1;
    }
}

// ---------------- K4: weighted_j = sum_n w_j(s_n) * (M[j]·x_n + c2_j) -----
// Wave-uniform agents: x via scalar loads (SMEM pipe), M rows in VGPRs,
// lane owns channels j and j+64. No LDS at all.
__global__ void __launch_bounds__(256) k4_main(
        const float* __restrict__ X,
        const float* __restrict__ Mt,      // [64][128]
        const float* __restrict__ c2,      // [128]
        const unsigned* __restrict__ mm,
        const float* __restrict__ scores,
        const float2* __restrict__ tab,    // pair table
        const int* __restrict__ selfp,
        float* __restrict__ wgt,
        int N, int APW)
{
    const int lane = threadIdx.x & 63;
    const int wid = __builtin_amdgcn_readfirstlane(blockIdx.x*4 + (threadIdx.x >> 6));
    const int j0 = lane, j1 = lane + 64;
    const int a0 = wid * APW;
    const int a1 = min(N, a0 + APW);

    float4 M0[16], M1[16];
    #pragma unroll
    for (int q = 0; q < 16; ++q) {   // coalesced dword loads from Mt
        M0[q] = make_float4(Mt[(4*q+0)*128 + j0], Mt[(4*q+1)*128 + j0],
                            Mt[(4*q+2)*128 + j0], Mt[(4*q+3)*128 + j0]);
        M1[q] = make_float4(Mt[(4*q+0)*128 + j1], Mt[(4*q+1)*128 + j1],
                            Mt[(4*q+2)*128 + j1], Mt[(4*q+3)*128 + j1]);
    }
    const float cc0 = c2[j0], cc1 = c2[j1];
    const float smin = decf(mm[0]), smax = decf(mm[1]);
    const float inv_step = (smax > smin) ? (float)(TBL - 1) / (smax - smin) : 0.f;
    const int self = *selfp;

    float rho0 = 0.f, rho1 = 0.f;
    if (a0 < a1) {
        float fc; float2 t0c, t1c;
        {   // prologue: table pair for first agent
            const float s = scores[a0];
            const float fi = (s - smin) * inv_step;
            int ii = (int)fi; ii = max(0, min(TBL - 2, ii));
            fc = fi - (float)ii;
            t0c = tab[ii*128 + j0]; t1c = tab[ii*128 + j1];
        }
        for (int n = a0; n < a1; ++n) {
            float fn = 0.f; float2 t0n = t0c, t1n = t1c;
            if (n + 1 < a1) {   // issue next agent's score+table (1-deep pipeline)
                const float s = scores[n + 1];
                const float fi = (s - smin) * inv_step;
                int ii = (int)fi; ii = max(0, min(TBL - 2, ii));
                fn = fi - (float)ii;
                t0n = tab[ii*128 + j0]; t1n = tab[ii*128 + j1];
            }
            const float w0 = t0c.x + fc * (t0c.y - t0c.x);
            const float w1 = t1c.x + fc * (t1c.y - t1c.x);
            const float4* xr = (const float4*)(X + ((size_t)n << 6));  // uniform -> s_load
            float a00=0.f,a01=0.f,a02=0.f,a03=0.f;
            float b00=0.f,b01=0.f,b02=0.f,b03=0.f;
            #pragma unroll
            for (int q = 0; q < 16; ++q) {
                const float4 xv = xr[q];
                a00 = __builtin_fmaf(M0[q].x, xv.x, a00);
                a01 = __builtin_fmaf(M0[q].y, xv.y, a01);
                a02 = __builtin_fmaf(M0[q].z, xv.z, a02);
                a03 = __builtin_fmaf(M0[q].w, xv.w, a03);
                b00 = __builtin_fmaf(M1[q].x, xv.x, b00);
                b01 = __builtin_fmaf(M1[q].y, xv.y, b01);
                b02 = __builtin_fmaf(M1[q].z, xv.z, b02);
                b03 = __builtin_fmaf(M1[q].w, xv.w, b03);
            }
            const float v0 = (a00 + a01) + (a02 + a03) + cc0;
            const float v1 = (b00 + b01) + (b02 + b03) + cc1;
            if (n != self) {
                rho0 = __builtin_fmaf(w0, v0, rho0);
                rho1 = __builtin_fmaf(w1, v1, rho1);
            }
            fc = fn; t0c = t0n; t1c = t1n;
        }
    }
    const int cpy = wid & 31;
    atomicAdd(&wgt[cpy*128 + j0], rho0);
    atomicAdd(&wgt[cpy*128 + j1], rho1);
}

// ---------------- K5: critic head ----------------------------------------
__global__ void __launch_bounds__(128) k5_final(
        const float* __restrict__ Wo1, const float* __restrict__ bo1,
        const float* __restrict__ Wo2, const float* __restrict__ bo2,
        float* ws, float* out)
{
    __shared__ float es[128], wg[128], red[128];
    const int t = threadIdx.x;
    es[t] = ws[OFF_EMB + t];
    float s = 0.f;
    for (int c = 0; c < 32; ++c) s += ws[OFF_WGT + c*128 + t];
    wg[t] = s;
    __syncthreads();
    const float4* wA = (const float4*)(Wo1 + t*256);
    float ax = 0.f, ay = 0.f, az = 0.f, aw = 0.f;
    #pragma unroll 8
    for (int i = 0; i < 32; ++i) {
        const float4 wv = wA[i];
        const float4 ev = ((const float4*)es)[i];
        ax = __builtin_fmaf(wv.x, ev.x, ax);
        ay = __builtin_fmaf(wv.y, ev.y, ay);
        az = __builtin_fmaf(wv.z, ev.z, az);
        aw = __builtin_fmaf(wv.w, ev.w, aw);
    }
    #pragma unroll 8
    for (int i = 0; i < 32; ++i) {
        const float4 wv = wA[32 + i];
        const float4 gv = ((const float4*)wg)[i];
        ax = __builtin_fmaf(wv.x, gv.x, ax);
        ay = __builtin_fmaf(wv.y, gv.y, ay);
        az = __builtin_fmaf(wv.z, gv.z, az);
        aw = __builtin_fmaf(wv.w, gv.w, aw);
    }
    const float acc = ((ax + ay) + (az + aw)) + bo1[t];
    red[t] = fmaxf(acc, 0.f) * Wo2[t];
    __syncthreads();
    for (int m = 64; m >= 1; m >>= 1) {
        if (t < m) red[t] += red[t + m];
        __syncthreads();
    }
    if (t == 0) out[0] = red[0] + bo2[0];
}

extern "C" void kernel_launch(void* const* d_in, const int* in_sizes, int n_in,
                              void* d_out, int out_size, void* d_ws, size_t ws_size,
                              hipStream_t stream)
{
    const float* X   = (const float*)d_in[0];
    const float* We  = (const float*)d_in[1];
    const float* be  = (const float*)d_in[2];
    const float* Wv  = (const float*)d_in[3];
    const float* Wq  = (const float*)d_in[4];
    const float* bq  = (const float*)d_in[5];
    const float* Wk  = (const float*)d_in[6];
    const float* bk  = (const float*)d_in[7];
    const float* W1  = (const float*)d_in[8];
    const float* b1  = (const float*)d_in[9];
    const float* W2  = (const float*)d_in[10];
    const float* b2  = (const float*)d_in[11];
    const float* W3  = (const float*)d_in[12];
    const float* b3  = (const float*)d_in[13];
    const float* Wo1 = (const float*)d_in[14];
    const float* bo1 = (const float*)d_in[15];
    const float* Wo2 = (const float*)d_in[16];
    const float* bo2 = (const float*)d_in[17];
    const int* selfp = (const int*)d_in[18];
    float* ws = (float*)d_ws;
    float* out = (float*)d_out;

    const int N = in_sizes[0] / 64;
    const int offTab = OFF_SCORES + ((N + 63) & ~63);   // even -> float2-aligned
    const int nwaves = 768 * 4;
    const int APW = (N + nwaves - 1) / nwaves;

    k1_prep<<<210, 256, 0, stream>>>(X, We, be, Wv, Wq, bq, Wk, bk, W1, b1, W2, W3, selfp, ws);
    k2_scores<<<1024, 256, 0, stream>>>((const float4*)X, ws, N);
    k3_l12<<<256, 512, 0, stream>>>((const float2*)(ws + OFF_W1B1), ws + OFF_W2T,
                                    b2, (const unsigned*)(ws + OFF_MM), ws + OFF_H2G);
    k3_l3<<<256, 256, 0, stream>>>(ws + OFF_H2G, ws + OFF_W3T, b3,
                                   (const unsigned*)(ws + OFF_MM), ws + offTab);
    k4_main<<<768, 256, 0, stream>>>(X, ws + OFF_MT, ws + OFF_C2,
                                     (const unsigned*)(ws + OFF_MM), ws + OFF_SCORES,
                                     (const float2*)(ws + offTab), selfp,
                                     ws + OFF_WGT, N, APW);
    k5_final<<<1, 128, 0, stream>>>(Wo1, bo1, Wo2, bo2, ws, out);
}

// Round 4
// 204.676 us; speedup vs baseline: 1.3868x; 1.0956x over previous
//
#include <hip/hip_runtime.h>
#include <math.h>

#define TBL 512
#define SBLK 512   // score blocks in k12

// workspace layout (float offsets)
#define OFF_MM     64       // 2 floats: smin, smax (written by k3a)
#define OFF_C2     128      // 128
#define OFF_EMB    256      // 128
#define OFF_MT     512      // 64*128  (M transposed: Mt[d][j])
#define OFF_WGT    8704     // 32*128 accumulator copies
#define OFF_BMIN   12800    // SBLK per-block minima
#define OFF_BMAX   13312    // SBLK per-block maxima
#define OFF_H2G    13824    // 256*TBL   h2g[c*TBL + e]
#define OFF_SCORES 144896   // N (padded); pair table follows at runtime offset

// ---------------- K12: prep (emb, Mt, c2, wgt-zero) + scores + block minmax
__global__ void __launch_bounds__(256) k12(
        const float* __restrict__ X,  const float* __restrict__ We,
        const float* __restrict__ be, const float* __restrict__ Wv,
        const float* __restrict__ Wq, const float* __restrict__ bq,
        const float* __restrict__ Wk, const float* __restrict__ bk,
        const int* __restrict__ selfp, float* __restrict__ ws,
        int N, int APB)
{
    const int b = blockIdx.x, t = threadIdx.x;
    if (b == 0) {
        // self embedding (for k5) + zero the weighted accumulators
        const int self = *selfp;
        const float4* xs4 = (const float4*)(X + (size_t)self * 64);
        if (t < 128) {
            const float4* wr = (const float4*)(We + t*64);
            float ax = 0.f, ay = 0.f, az = 0.f, aw = 0.f;
            #pragma unroll
            for (int q = 0; q < 16; ++q) {
                const float4 wv = wr[q];
                const float4 xv = xs4[q];     // uniform -> s_load
                ax = __builtin_fmaf(wv.x, xv.x, ax);
                ay = __builtin_fmaf(wv.y, xv.y, ay);
                az = __builtin_fmaf(wv.z, xv.z, az);
                aw = __builtin_fmaf(wv.w, xv.w, aw);
            }
            ws[OFF_EMB + t] = ((ax + ay) + (az + aw)) + be[t];
        }
        for (int i = t; i < 32*128; i += 256) ws[OFF_WGT + i] = 0.f;
    } else if (b <= 128) {
        const int r = b - 1;   // row r of M = (Wv @ We); store transposed Mt[d][r]
        if (t < 64) {
            float acc = 0.f;
            #pragma unroll 8
            for (int e = 0; e < 128; ++e)
                acc = __builtin_fmaf(Wv[r*128 + e], We[e*64 + t], acc);
            ws[OFF_MT + t*128 + r] = acc;
        } else if (t == 64) {
            float acc = 0.f;
            for (int e = 0; e < 128; ++e)
                acc = __builtin_fmaf(Wv[r*128 + e], be[e], acc);
            ws[OFF_C2 + r] = acc;
        }
    } else {
        // ---- score block: redundantly fold v = We^T Wk^T q / sqrt(E) ----
        __shared__ float emb[128], qv[128], uu[128], vv[64];
        __shared__ float s0s;
        const int self = *selfp;
        const float4* xs4 = (const float4*)(X + (size_t)self * 64);
        if (t < 128) {
            const float4* wr = (const float4*)(We + t*64);
            float ax = 0.f, ay = 0.f, az = 0.f, aw = 0.f;
            #pragma unroll
            for (int q = 0; q < 16; ++q) {
                const float4 wv = wr[q];
                const float4 xv = xs4[q];
                ax = __builtin_fmaf(wv.x, xv.x, ax);
                ay = __builtin_fmaf(wv.y, xv.y, ay);
                az = __builtin_fmaf(wv.z, xv.z, az);
                aw = __builtin_fmaf(wv.w, xv.w, aw);
            }
            emb[t] = ((ax + ay) + (az + aw)) + be[t];
        }
        __syncthreads();
        if (t < 128) {
            const float4* wr = (const float4*)(Wq + t*128);
            float ax = 0.f, ay = 0.f, az = 0.f, aw = 0.f;
            #pragma unroll 8
            for (int q = 0; q < 32; ++q) {
                const float4 wv = wr[q];
                const float4 ev = ((const float4*)emb)[q];
                ax = __builtin_fmaf(wv.x, ev.x, ax);
                ay = __builtin_fmaf(wv.y, ev.y, ay);
                az = __builtin_fmaf(wv.z, ev.z, az);
                aw = __builtin_fmaf(wv.w, ev.w, aw);
            }
            qv[t] = ((ax + ay) + (az + aw)) + bq[t];
        }
        __syncthreads();
        if (t < 128) {
            float acc = 0.f;
            #pragma unroll 8
            for (int e = 0; e < 128; ++e)
                acc = __builtin_fmaf(Wk[e*128 + t], qv[e], acc);   // coalesced
            uu[t] = acc;
        }
        __syncthreads();
        const float rs = 0.08838834764831845f;  // 1/sqrt(128)
        if (t < 64) {
            float acc = 0.f;
            #pragma unroll 8
            for (int e = 0; e < 128; ++e)
                acc = __builtin_fmaf(We[e*64 + t], uu[e], acc);    // coalesced
            vv[t] = acc * rs;
        } else if (t == 64) {
            float acc = 0.f;
            for (int e = 0; e < 128; ++e)
                acc += be[e]*uu[e] + bk[e]*qv[e];
            s0s = acc * rs;
        }
        __syncthreads();

        // ---- scores for this block's agent slice ----
        const int s = b - 129;
        const int base = s * APB;
        const int n1 = min(N, base + APB);
        const int l16 = t & 15;
        const int slot = t >> 4;        // 16 agents per 256-thread pass
        const float4 vch = *(const float4*)(vv + l16*4);
        const float s0 = s0s;
        const float4* X4 = (const float4*)X;
        float* scores = ws + OFF_SCORES;
        float smin = INFINITY, smax = -INFINITY;
        for (int n = base + slot; n < n1; n += 16) {
            const float4 xv = X4[(size_t)n*16 + l16];
            float sc = xv.x*vch.x + xv.y*vch.y + xv.z*vch.z + xv.w*vch.w;
            sc += __shfl_xor(sc, 1);
            sc += __shfl_xor(sc, 2);
            sc += __shfl_xor(sc, 4);
            sc += __shfl_xor(sc, 8);
            sc += s0;
            if (l16 == 0) scores[n] = sc;
            smin = fminf(smin, sc);
            smax = fmaxf(smax, sc);
        }
        #pragma unroll
        for (int m = 32; m >= 1; m >>= 1) {
            smin = fminf(smin, __shfl_xor(smin, m));
            smax = fmaxf(smax, __shfl_xor(smax, m));
        }
        __shared__ float rmn[4], rmx[4];
        const int wv = t >> 6;
        if ((t & 63) == 0) { rmn[wv] = smin; rmx[wv] = smax; }
        __syncthreads();
        if (t == 0) {
            ws[OFF_BMIN + s] = fminf(fminf(rmn[0], rmn[1]), fminf(rmn[2], rmn[3]));
            ws[OFF_BMAX + s] = fmaxf(fmaxf(rmx[0], rmx[1]), fmaxf(rmx[2], rmx[3]));
        }
    }
}

// ---------------- K3a: minmax reduce + layers 1+2 -> h2g[c][e] ------------
// TBL/4 blocks x 512 thr. Thread: c=t&255, eh=t>>8 -> 2 entries each.
__global__ void __launch_bounds__(512) k3a(
        const float* __restrict__ W1, const float* __restrict__ b1,
        const float* __restrict__ W2, const float* __restrict__ b2,
        float* __restrict__ ws, int nsb)
{
    __shared__ float rmn[8], rmx[8];
    const int t = threadIdx.x;
    float mn = (t < nsb) ? ws[OFF_BMIN + t] : INFINITY;
    float mx = (t < nsb) ? ws[OFF_BMAX + t] : -INFINITY;
    #pragma unroll
    for (int m = 32; m >= 1; m >>= 1) {
        mn = fminf(mn, __shfl_xor(mn, m));
        mx = fmaxf(mx, __shfl_xor(mx, m));
    }
    if ((t & 63) == 0) { rmn[t >> 6] = mn; rmx[t >> 6] = mx; }
    __syncthreads();
    float smin = rmn[0], smax = rmx[0];
    #pragma unroll
    for (int w = 1; w < 8; ++w) {
        smin = fminf(smin, rmn[w]);
        smax = fmaxf(smax, rmx[w]);
    }
    if (blockIdx.x == 0 && t == 0) { ws[OFF_MM] = smin; ws[OFF_MM + 1] = smax; }

    const float step = (smax - smin) / (float)(TBL - 1);
    const int c = t & 255;
    const int eh = t >> 8;
    const int eA = blockIdx.x*4 + eh*2;
    const float sA = smin + step * (float)eA;
    const float sB = smin + step * (float)(eA + 1);
    const float bb = b2[c];
    float a0 = bb, a1 = bb;
    const float4* w2r = (const float4*)(W2 + c*512);   // per-lane row stream
    #pragma unroll 4
    for (int kq = 0; kq < 128; ++kq) {
        const float4 w2 = w2r[kq];
        #pragma unroll
        for (int i = 0; i < 4; ++i) {
            const int k = kq*4 + i;
            const float w1v = W1[k];                   // uniform -> s_load
            const float b1v = b1[k];
            const float h1A = fmaxf(0.f, __builtin_fmaf(sA, w1v, b1v));
            const float h1B = fmaxf(0.f, __builtin_fmaf(sB, w1v, b1v));
            const float wc = (i == 0) ? w2.x : (i == 1) ? w2.y : (i == 2) ? w2.z : w2.w;
            a0 = __builtin_fmaf(wc, h1A, a0);
            a1 = __builtin_fmaf(wc, h1B, a1);
        }
    }
    *(float2*)(ws + OFF_H2G + c*TBL + eA) = make_float2(fmaxf(0.f, a0), fmaxf(0.f, a1));
}

// ---------------- K3b: layer 3 + softmax + pair table ---------------------
// TBL/4 blocks x 256 thr. Thread: j=t&127, kh=t>>7.
__global__ void __launch_bounds__(256) k3b(
        const float* __restrict__ W3, const float* __restrict__ b3,
        const float* __restrict__ h2g,     // ws + OFF_H2G
        float* __restrict__ tab)           // pair table
{
    __shared__ float sm[4][128];
    const int t = threadIdx.x;
    const int j = t & 127;
    const int kh = t >> 7;
    const int e0 = blockIdx.x * 4;
    float acc[4] = {0.f, 0.f, 0.f, 0.f};
    const float4* w3r = (const float4*)(W3 + j*256 + kh*128);  // per-lane row
    #pragma unroll 4
    for (int kq = 0; kq < 32; ++kq) {
        const float4 w3 = w3r[kq];
        #pragma unroll
        for (int i = 0; i < 4; ++i) {
            const int k = kh*128 + kq*4 + i;
            const float4 h2v = *(const float4*)(h2g + k*TBL + e0);  // uniform -> s_load
            const float wc = (i == 0) ? w3.x : (i == 1) ? w3.y : (i == 2) ? w3.z : w3.w;
            acc[0] = __builtin_fmaf(wc, h2v.x, acc[0]);
            acc[1] = __builtin_fmaf(wc, h2v.y, acc[1]);
            acc[2] = __builtin_fmaf(wc, h2v.z, acc[2]);
            acc[3] = __builtin_fmaf(wc, h2v.w, acc[3]);
        }
    }
    if (kh == 0) {
        const float bb = b3[j];
        #pragma unroll
        for (int e = 0; e < 4; ++e) sm[e][j] = acc[e] + bb;
    }
    __syncthreads();
    if (kh == 1) {
        #pragma unroll
        for (int e = 0; e < 4; ++e) sm[e][j] = fmaxf(0.f, sm[e][j] + acc[e]);
    }
    __syncthreads();
    // softmax: wave w handles entry w (4 waves of 64)
    const int w = t >> 6, lane = t & 63;
    const float v0 = sm[w][lane];
    const float v1 = sm[w][lane + 64];
    float m = fmaxf(v0, v1);
    #pragma unroll
    for (int msk = 1; msk < 64; msk <<= 1) m = fmaxf(m, __shfl_xor(m, msk));
    float p = __expf(v0 - m) + __expf(v1 - m);
    #pragma unroll
    for (int msk = 1; msk < 64; msk <<= 1) p += __shfl_xor(p, msk);
    const float inv = 1.f / p;
    const int row = e0 + w;
    const float g0 = __expf(v0 - m) * inv;
    const float g1 = __expf(v1 - m) * inv;
    if (row < TBL - 1) {
        tab[2*(row*128 + lane) + 0]      = g0;
        tab[2*(row*128 + lane + 64) + 0] = g1;
    }
    if (row >= 1) {
        tab[2*((row-1)*128 + lane) + 1]      = g0;
        tab[2*((row-1)*128 + lane + 64) + 1] = g1;
    }
}

// ---------------- K4: weighted_j = sum_n w_j(s_n) * (M[j]·x_n + c2_j) -----
__global__ void __launch_bounds__(256) k4_main(
        const float* __restrict__ X,
        const float* __restrict__ Mt,      // [64][128]
        const float* __restrict__ c2,      // [128]
        const float* __restrict__ mm,      // {smin, smax}
        const float* __restrict__ scores,
        const float2* __restrict__ tab,    // pair table
        const int* __restrict__ selfp,
        float* __restrict__ wgt,
        int N, int APW)
{
    const int lane = threadIdx.x & 63;
    const int wid = __builtin_amdgcn_readfirstlane(blockIdx.x*4 + (threadIdx.x >> 6));
    const int j0 = lane, j1 = lane + 64;
    const int a0 = wid * APW;
    const int a1 = min(N, a0 + APW);

    float4 M0[16], M1[16];
    #pragma unroll
    for (int q = 0; q < 16; ++q) {   // coalesced dword loads from Mt
        M0[q] = make_float4(Mt[(4*q+0)*128 + j0], Mt[(4*q+1)*128 + j0],
                            Mt[(4*q+2)*128 + j0], Mt[(4*q+3)*128 + j0]);
        M1[q] = make_float4(Mt[(4*q+0)*128 + j1], Mt[(4*q+1)*128 + j1],
                            Mt[(4*q+2)*128 + j1], Mt[(4*q+3)*128 + j1]);
    }
    const float cc0 = c2[j0], cc1 = c2[j1];
    const float smin = mm[0], smax = mm[1];
    const float inv_step = (smax > smin) ? (float)(TBL - 1) / (smax - smin) : 0.f;
    const int self = *selfp;

    float rho0 = 0.f, rho1 = 0.f;
    if (a0 < a1) {
        float fc; float2 t0c, t1c;
        {   // prologue: table pair for first agent
            const float s = scores[a0];
            const float fi = (s - smin) * inv_step;
            int ii = (int)fi; ii = max(0, min(TBL - 2, ii));
            fc = fi - (float)ii;
            t0c = tab[ii*128 + j0]; t1c = tab[ii*128 + j1];
        }
        for (int n = a0; n < a1; ++n) {
            float fn = 0.f; float2 t0n = t0c, t1n = t1c;
            if (n + 1 < a1) {   // 1-deep pipeline on score+table loads
                const float s = scores[n + 1];
                const float fi = (s - smin) * inv_step;
                int ii = (int)fi; ii = max(0, min(TBL - 2, ii));
                fn = fi - (float)ii;
                t0n = tab[ii*128 + j0]; t1n = tab[ii*128 + j1];
            }
            const float w0 = t0c.x + fc * (t0c.y - t0c.x);
            const float w1 = t1c.x + fc * (t1c.y - t1c.x);
            const float4* xr = (const float4*)(X + ((size_t)n << 6));  // uniform -> s_load
            float a00=0.f,a01=0.f,a02=0.f,a03=0.f;
            float b00=0.f,b01=0.f,b02=0.f,b03=0.f;
            #pragma unroll
            for (int q = 0; q < 16; ++q) {
                const float4 xv = xr[q];
                a00 = __builtin_fmaf(M0[q].x, xv.x, a00);
                a01 = __builtin_fmaf(M0[q].y, xv.y, a01);
                a02 = __builtin_fmaf(M0[q].z, xv.z, a02);
                a03 = __builtin_fmaf(M0[q].w, xv.w, a03);
                b00 = __builtin_fmaf(M1[q].x, xv.x, b00);
                b01 = __builtin_fmaf(M1[q].y, xv.y, b01);
                b02 = __builtin_fmaf(M1[q].z, xv.z, b02);
                b03 = __builtin_fmaf(M1[q].w, xv.w, b03);
            }
            const float v0 = (a00 + a01) + (a02 + a03) + cc0;
            const float v1 = (b00 + b01) + (b02 + b03) + cc1;
            if (n != self) {
                rho0 = __builtin_fmaf(w0, v0, rho0);
                rho1 = __builtin_fmaf(w1, v1, rho1);
            }
            fc = fn; t0c = t0n; t1c = t1n;
        }
    }
    const int cpy = wid & 31;
    atomicAdd(&wgt[cpy*128 + j0], rho0);
    atomicAdd(&wgt[cpy*128 + j1], rho1);
}

// ---------------- K5: critic head ----------------------------------------
__global__ void __launch_bounds__(128) k5_final(
        const float* __restrict__ Wo1, const float* __restrict__ bo1,
        const float* __restrict__ Wo2, const float* __restrict__ bo2,
        float* ws, float* out)
{
    __shared__ float es[128], wg[128], red[128];
    const int t = threadIdx.x;
    es[t] = ws[OFF_EMB + t];
    float s = 0.f;
    for (int c = 0; c < 32; ++c) s += ws[OFF_WGT + c*128 + t];
    wg[t] = s;
    __syncthreads();
    const float4* wA = (const float4*)(Wo1 + t*256);
    float ax = 0.f, ay = 0.f, az = 0.f, aw = 0.f;
    #pragma unroll 8
    for (int i = 0; i < 32; ++i) {
        const float4 wv = wA[i];
        const float4 ev = ((const float4*)es)[i];
        ax = __builtin_fmaf(wv.x, ev.x, ax);
        ay = __builtin_fmaf(wv.y, ev.y, ay);
        az = __builtin_fmaf(wv.z, ev.z, az);
        aw = __builtin_fmaf(wv.w, ev.w, aw);
    }
    #pragma unroll 8
    for (int i = 0; i < 32; ++i) {
        const float4 wv = wA[32 + i];
        const float4 gv = ((const float4*)wg)[i];
        ax = __builtin_fmaf(wv.x, gv.x, ax);
        ay = __builtin_fmaf(wv.y, gv.y, ay);
        az = __builtin_fmaf(wv.z, gv.z, az);
        aw = __builtin_fmaf(wv.w, gv.w, aw);
    }
    const float acc = ((ax + ay) + (az + aw)) + bo1[t];
    red[t] = fmaxf(acc, 0.f) * Wo2[t];
    __syncthreads();
    for (int m = 64; m >= 1; m >>= 1) {
        if (t < m) red[t] += red[t + m];
        __syncthreads();
    }
    if (t == 0) out[0] = red[0] + bo2[0];
}

extern "C" void kernel_launch(void* const* d_in, const int* in_sizes, int n_in,
                              void* d_out, int out_size, void* d_ws, size_t ws_size,
                              hipStream_t stream)
{
    const float* X   = (const float*)d_in[0];
    const float* We  = (const float*)d_in[1];
    const float* be  = (const float*)d_in[2];
    const float* Wv  = (const float*)d_in[3];
    const float* Wq  = (const float*)d_in[4];
    const float* bq  = (const float*)d_in[5];
    const float* Wk  = (const float*)d_in[6];
    const float* bk  = (const float*)d_in[7];
    const float* W1  = (const float*)d_in[8];
    const float* b1  = (const float*)d_in[9];
    const float* W2  = (const float*)d_in[10];
    const float* b2  = (const float*)d_in[11];
    const float* W3  = (const float*)d_in[12];
    const float* b3  = (const float*)d_in[13];
    const float* Wo1 = (const float*)d_in[14];
    const float* bo1 = (const float*)d_in[15];
    const float* Wo2 = (const float*)d_in[16];
    const float* bo2 = (const float*)d_in[17];
    const int* selfp = (const int*)d_in[18];
    float* ws = (float*)d_ws;
    float* out = (float*)d_out;

    const int N = in_sizes[0] / 64;
    const int offTab = OFF_SCORES + ((N + 63) & ~63);   // even -> float2-aligned
    const int APB = (N + SBLK - 1) / SBLK;
    const int nwaves = 768 * 4;
    const int APW = (N + nwaves - 1) / nwaves;

    k12<<<129 + SBLK, 256, 0, stream>>>(X, We, be, Wv, Wq, bq, Wk, bk, selfp, ws, N, APB);
    k3a<<<TBL/4, 512, 0, stream>>>(W1, b1, W2, b2, ws, SBLK);
    k3b<<<TBL/4, 256, 0, stream>>>(W3, b3, ws + OFF_H2G, ws + offTab);
    k4_main<<<768, 256, 0, stream>>>(X, ws + OFF_MT, ws + OFF_C2, ws + OFF_MM,
                                     ws + OFF_SCORES, (const float2*)(ws + offTab),
                                     selfp, ws + OFF_WGT, N, APW);
    k5_final<<<1, 128, 0, stream>>>(Wo1, bo1, Wo2, bo2, ws, out);
}